// Round 19
// baseline (223.977 us; speedup 1.0000x reference)
//
#include <hip/hip_runtime.h>

#define NN 50000
#define NE 800000
#define DD 128
#define NL 3
#define ELLW 64
#define MT_TOTAL (NN / 16)                      // 3125 tiles of 16 rows
#define MT_PER_XCD 391                          // tiles per partition (grid pad 3128)
#define NODES_PER_XCD (MT_PER_XCD * 16)         // 6256
#define NPAIR 196                               // ceil(391/2) tile-pairs per partition
#define SCAT_BLKS (MT_PER_XCD * 8)              // 3128
#define SCAT_CHUNK 2048
#define PACK_BLKS ((6 * 2048 + 255) / 256)      // 48
#define INIT_BLKS 3128

typedef short bf16x8 __attribute__((ext_vector_type(8)));
typedef float f32x4 __attribute__((ext_vector_type(4)));
typedef _Float16 half8 __attribute__((ext_vector_type(8)));
typedef unsigned short u16x8 __attribute__((ext_vector_type(8)));

__device__ __forceinline__ unsigned short f2bf(float x) {
  unsigned u = __float_as_uint(x);
  u += 0x7FFFu + ((u >> 16) & 1u);          // RTN-even
  return (unsigned short)(u >> 16);
}
__device__ __forceinline__ float bf2f(unsigned short h) {
  return __uint_as_float(((unsigned)h) << 16);
}
__device__ __forceinline__ void cvt8(const float* zz, bf16x8* hi, bf16x8* lo) {
#pragma unroll
  for (int i = 0; i < 8; ++i) {
    unsigned short h = f2bf(zz[i]);
    (*hi)[i] = (short)h;
    (*lo)[i] = (short)f2bf(zz[i] - bf2f(h));
  }
}

// ---------------- fused prologue: XCD-filtered ELL build + W pack + fp16 mirror ----
__global__ __launch_bounds__(256) void prologue_k(
    const int* __restrict__ ei, int* __restrict__ cnt, unsigned short* __restrict__ ell,
    const float* __restrict__ W1, const float* __restrict__ W2,
    unsigned short* __restrict__ Wp,
    const float* __restrict__ X, _Float16* __restrict__ Xh)
{
  int b = blockIdx.x;
  if (b < SCAT_BLKS) {
    int g = b & 7, chunk = b >> 3;
    int lo = g * NODES_PER_XCD, hi = lo + NODES_PER_XCD;
    int base = chunk * SCAT_CHUNK + threadIdx.x * 8;
    if (base + 7 < NE) {
      int4 d0 = *(const int4*)(ei + NE + base);
      int4 d1 = *(const int4*)(ei + NE + base + 4);
      int4 s0 = *(const int4*)(ei + base);
      int4 s1 = *(const int4*)(ei + base + 4);
      int dd[8] = {d0.x, d0.y, d0.z, d0.w, d1.x, d1.y, d1.z, d1.w};
      int ss[8] = {s0.x, s0.y, s0.z, s0.w, s1.x, s1.y, s1.z, s1.w};
#pragma unroll
      for (int i = 0; i < 8; ++i) {
        int d = dd[i];
        if (d >= lo && d < hi) {
          int pos = atomicAdd(&cnt[d], 1);
          if (pos < ELLW) ell[(size_t)d * ELLW + pos] = (unsigned short)ss[i];
        }
      }
    } else {
      for (int e = base; e < NE; ++e) {
        int d = ei[NE + e];
        if (d >= lo && d < hi) {
          int pos = atomicAdd(&cnt[d], 1);
          if (pos < ELLW) ell[(size_t)d * ELLW + pos] = (unsigned short)ei[e];
        }
      }
    }
  } else if (b < SCAT_BLKS + PACK_BLKS) {
    int t = (b - SCAT_BLKS) * 256 + threadIdx.x;
    if (t < 6 * 2048) {
      int m = t >> 11;
      int rem = t & 2047;              // (nt*4+ks)*64 + lane
      int l = rem & 63;
      int ntks = rem >> 6;
      int ks = ntks & 3, nt = ntks >> 2;
      const float* W = (m < 3) ? (W1 + (size_t)m * DD * DD) : (W2 + (size_t)(m - 3) * DD * DD);
      int col = nt * 16 + (l & 15);
      int k0 = ks * 32 + (l >> 4) * 8;
      unsigned short* hi = Wp + (size_t)m * 2 * DD * DD + (size_t)rem * 8;
      unsigned short* lo = hi + DD * DD;
#pragma unroll
      for (int i = 0; i < 8; ++i) {
        float w = W[(size_t)(k0 + i) * DD + col];
        unsigned short h = f2bf(w);
        hi[i] = h;
        lo[i] = f2bf(w - bf2f(h));
      }
    }
  } else {
    int bb = b - SCAT_BLKS - PACK_BLKS;
    int g = bb & 7, ii = bb >> 3;
    int mt = g * MT_PER_XCD + ii;
    if (mt < MT_TOTAL) {
      size_t base = (size_t)mt * 16 * DD + threadIdx.x * 8;
      const float4* p = (const float4*)(X + base);
      float4 a = p[0], bb2 = p[1];
      half8 h;
      h[0] = (_Float16)a.x;   h[1] = (_Float16)a.y;   h[2] = (_Float16)a.z;   h[3] = (_Float16)a.w;
      h[4] = (_Float16)bb2.x; h[5] = (_Float16)bb2.y; h[6] = (_Float16)bb2.z; h[7] = (_Float16)bb2.w;
      *(half8*)(Xh + base) = h;
    }
  }
}

// ---------------- single-kernel per-partition counting sort -> perm ----------------
__global__ __launch_bounds__(256) void sort_k(const int* __restrict__ cnt,
                                              int* __restrict__ perm) {
  __shared__ int lh[ELLW + 1];
  __shared__ int cur[ELLW + 1];
  int g = blockIdx.x;
  int base = g * NODES_PER_XCD;
  int nend = base + NODES_PER_XCD; if (nend > NN) nend = NN;
  for (int i = threadIdx.x; i <= ELLW; i += 256) lh[i] = 0;
  __syncthreads();
  for (int n = base + threadIdx.x; n < nend; n += 256) {
    int deg = cnt[n]; deg = deg > ELLW ? ELLW : deg;
    atomicAdd(&lh[deg], 1);
  }
  __syncthreads();
  if (threadIdx.x == 0) {
    int run = base;
    for (int b = 0; b <= ELLW; ++b) { cur[b] = run; run += lh[b]; }
  }
  __syncthreads();
  for (int n = base + threadIdx.x; n < nend; n += 256) {
    int deg = cnt[n]; deg = deg > ELLW ? ELLW : deg;
    int rank = atomicAdd(&cur[deg], 1);
    perm[rank] = n | (deg << 16);
  }
}

// ---------------- fused layer: 2 tiles/block, interleaved gathers, shared W-frags ----
template<int OUT_F32>
__global__ __launch_bounds__(256) void fused_layer_k(
    const _Float16* __restrict__ Xh_in,
    const int* __restrict__ perm, const unsigned short* __restrict__ ell,
    const float* __restrict__ eps, int layer,
    const unsigned short* __restrict__ Wp1, const float* __restrict__ b1,
    const unsigned short* __restrict__ Wp2, const float* __restrict__ b2,
    float* __restrict__ Xf_out, _Float16* __restrict__ Xh_out)
{
  __shared__ float ztile[2][16 * 132];
  __shared__ unsigned short rtile[2][16 * 136];
  const int part = blockIdx.x & 7;
  const int pi = blockIdx.x >> 3;                 // 0..195
  const int pis = (pi * 5) % NPAIR;               // gcd(5,196)=1: de-convoy shuffle
  const int iiA = pis * 2, iiB = pis * 2 + 1;
  const int mtA = part * MT_PER_XCD + iiA;
  const int mtB = part * MT_PER_XCD + iiB;
  const bool vA = (iiA < MT_PER_XCD) && (mtA < MT_TOTAL);
  const bool vB = (iiB < MT_PER_XCD) && (mtB < MT_TOTAL);
  const int w = threadIdx.x >> 6, l = threadIdx.x & 63;
  const int c = l & 15, grp = l >> 4;
  const int nl = w * 4 + grp;

  // ---- phase A: interleaved gather for tiles A and B (up to 16 loads in flight) ----
  {
    const float e1 = 1.0f + eps[layer];
    int peA = vA ? perm[mtA * 16 + nl] : 0;
    int peB = vB ? perm[mtB * 16 + nl] : 0;
    int nodeA = peA & 0xFFFF, degA = peA >> 16;
    int nodeB = peB & 0xFFFF, degB = peB >> 16;
    const unsigned short* elA = ell + (size_t)nodeA * ELLW;
    const unsigned short* elB = ell + (size_t)nodeB * ELLW;
    const u16x8* elA8 = (const u16x8*)elA;
    const u16x8* elB8 = (const u16x8*)elB;
    half8 svA = *(const half8*)(Xh_in + (size_t)nodeA * DD + c * 8);
    half8 svB = *(const half8*)(Xh_in + (size_t)nodeB * DD + c * 8);
    *(u16x8*)(rtile[0] + nl * 136 + c * 8) = *(const u16x8*)&svA;
    *(u16x8*)(rtile[1] + nl * 136 + c * 8) = *(const u16x8*)&svB;
    half8 accA = (half8)(_Float16)0.0f;
    half8 accB = (half8)(_Float16)0.0f;
    int nfA = degA >> 3, nfB = degB >> 3;
    int nf = nfA > nfB ? nfA : nfB;
    u16x8 nxtA, nxtB;
    if (nfA) nxtA = elA8[0];
    if (nfB) nxtB = elB8[0];
    for (int t = 0; t < nf; ++t) {
      bool dA = t < nfA, dB = t < nfB;
      half8 a0, a1, a2, a3, a4, a5, a6, a7;
      half8 b0, b1h, b2h, b3, b4, b5, b6, b7;
      u16x8 curA, curB;
      if (dA) {
        curA = nxtA;
        if (t + 1 < nfA) nxtA = elA8[t + 1];
        a0 = *(const half8*)(Xh_in + (size_t)curA[0] * DD + c * 8);
        a1 = *(const half8*)(Xh_in + (size_t)curA[1] * DD + c * 8);
        a2 = *(const half8*)(Xh_in + (size_t)curA[2] * DD + c * 8);
        a3 = *(const half8*)(Xh_in + (size_t)curA[3] * DD + c * 8);
        a4 = *(const half8*)(Xh_in + (size_t)curA[4] * DD + c * 8);
        a5 = *(const half8*)(Xh_in + (size_t)curA[5] * DD + c * 8);
        a6 = *(const half8*)(Xh_in + (size_t)curA[6] * DD + c * 8);
        a7 = *(const half8*)(Xh_in + (size_t)curA[7] * DD + c * 8);
      }
      if (dB) {
        curB = nxtB;
        if (t + 1 < nfB) nxtB = elB8[t + 1];
        b0  = *(const half8*)(Xh_in + (size_t)curB[0] * DD + c * 8);
        b1h = *(const half8*)(Xh_in + (size_t)curB[1] * DD + c * 8);
        b2h = *(const half8*)(Xh_in + (size_t)curB[2] * DD + c * 8);
        b3  = *(const half8*)(Xh_in + (size_t)curB[3] * DD + c * 8);
        b4  = *(const half8*)(Xh_in + (size_t)curB[4] * DD + c * 8);
        b5  = *(const half8*)(Xh_in + (size_t)curB[5] * DD + c * 8);
        b6  = *(const half8*)(Xh_in + (size_t)curB[6] * DD + c * 8);
        b7  = *(const half8*)(Xh_in + (size_t)curB[7] * DD + c * 8);
      }
      if (dA) accA += ((a0 + a1) + (a2 + a3)) + ((a4 + a5) + (a6 + a7));
      if (dB) accB += ((b0 + b1h) + (b2h + b3)) + ((b4 + b5) + (b6 + b7));
    }
    for (int j = nfA * 8; j < degA; ++j)
      accA += *(const half8*)(Xh_in + (size_t)elA[j] * DD + c * 8);
    for (int j = nfB * 8; j < degB; ++j)
      accB += *(const half8*)(Xh_in + (size_t)elB[j] * DD + c * 8);
    float za[8], zb[8];
#pragma unroll
    for (int i = 0; i < 8; ++i) {
      za[i] = fmaf(e1, (float)svA[i], (float)accA[i]);
      zb[i] = fmaf(e1, (float)svB[i], (float)accB[i]);
    }
    float* dA2 = ztile[0] + nl * 132 + c * 8;
    float* dB2 = ztile[1] + nl * 132 + c * 8;
    *(float4*)dA2       = make_float4(za[0], za[1], za[2], za[3]);
    *(float4*)(dA2 + 4) = make_float4(za[4], za[5], za[6], za[7]);
    *(float4*)dB2       = make_float4(zb[0], zb[1], zb[2], zb[3]);
    *(float4*)(dB2 + 4) = make_float4(zb[4], zb[5], zb[6], zb[7]);
  }
  __syncthreads();

  // ---- phase B: GEMM1 (Z @ W1) both tiles, shared W-frags; ReLU; H -> LDS ----
  f32x4 acc1A[2], acc1B[2];
#pragma unroll
  for (int nt = 0; nt < 2; ++nt) {
    acc1A[nt] = (f32x4){0.f, 0.f, 0.f, 0.f};
    acc1B[nt] = (f32x4){0.f, 0.f, 0.f, 0.f};
  }
  {
    const float* arowA = ztile[0] + (l & 15) * 132;
    const float* arowB = ztile[1] + (l & 15) * 132;
    const unsigned short* Whi = Wp1;
    const unsigned short* Wlo = Wp1 + DD * DD;
#pragma unroll
    for (int ks = 0; ks < 4; ++ks) {
      const float* zpA = arowA + ks * 32 + grp * 8;
      const float* zpB = arowB + ks * 32 + grp * 8;
      float zzA[8] = {zpA[0], zpA[1], zpA[2], zpA[3], zpA[4], zpA[5], zpA[6], zpA[7]};
      float zzB[8] = {zpB[0], zpB[1], zpB[2], zpB[3], zpB[4], zpB[5], zpB[6], zpB[7]};
      bf16x8 ahiA, aloA, ahiB, aloB;
      cvt8(zzA, &ahiA, &aloA);
      cvt8(zzB, &ahiB, &aloB);
#pragma unroll
      for (int nt = 0; nt < 2; ++nt) {
        int ntb = w * 2 + nt;
        size_t off = ((size_t)(ntb * 4 + ks) * 64 + l) * 8;
        bf16x8 bhi = *(const bf16x8*)(Whi + off);
        bf16x8 blo = *(const bf16x8*)(Wlo + off);
        acc1A[nt] = __builtin_amdgcn_mfma_f32_16x16x32_bf16(ahiA, bhi, acc1A[nt], 0, 0, 0);
        acc1A[nt] = __builtin_amdgcn_mfma_f32_16x16x32_bf16(ahiA, blo, acc1A[nt], 0, 0, 0);
        acc1A[nt] = __builtin_amdgcn_mfma_f32_16x16x32_bf16(aloA, bhi, acc1A[nt], 0, 0, 0);
        acc1B[nt] = __builtin_amdgcn_mfma_f32_16x16x32_bf16(ahiB, bhi, acc1B[nt], 0, 0, 0);
        acc1B[nt] = __builtin_amdgcn_mfma_f32_16x16x32_bf16(ahiB, blo, acc1B[nt], 0, 0, 0);
        acc1B[nt] = __builtin_amdgcn_mfma_f32_16x16x32_bf16(aloB, bhi, acc1B[nt], 0, 0, 0);
      }
    }
  }
  __syncthreads();   // all Z reads complete before H overwrites the tiles

  {
#pragma unroll
    for (int nt = 0; nt < 2; ++nt) {
      int ntb = w * 2 + nt;
      float bv = b1[ntb * 16 + c];
#pragma unroll
      for (int r = 0; r < 4; ++r) {
        ztile[0][(grp * 4 + r) * 132 + ntb * 16 + c] = fmaxf(acc1A[nt][r] + bv, 0.f);
        ztile[1][(grp * 4 + r) * 132 + ntb * 16 + c] = fmaxf(acc1B[nt][r] + bv, 0.f);
      }
    }
  }
  __syncthreads();

  // ---- phase C: GEMM2 (H @ W2) both tiles + bias + residual, write outputs ----
  f32x4 acc2A[2], acc2B[2];
#pragma unroll
  for (int nt = 0; nt < 2; ++nt) {
    acc2A[nt] = (f32x4){0.f, 0.f, 0.f, 0.f};
    acc2B[nt] = (f32x4){0.f, 0.f, 0.f, 0.f};
  }
  {
    const float* arowA = ztile[0] + (l & 15) * 132;
    const float* arowB = ztile[1] + (l & 15) * 132;
    const unsigned short* Whi = Wp2;
    const unsigned short* Wlo = Wp2 + DD * DD;
#pragma unroll
    for (int ks = 0; ks < 4; ++ks) {
      const float* hpA = arowA + ks * 32 + grp * 8;
      const float* hpB = arowB + ks * 32 + grp * 8;
      float hhA[8] = {hpA[0], hpA[1], hpA[2], hpA[3], hpA[4], hpA[5], hpA[6], hpA[7]};
      float hhB[8] = {hpB[0], hpB[1], hpB[2], hpB[3], hpB[4], hpB[5], hpB[6], hpB[7]};
      bf16x8 ahiA, aloA, ahiB, aloB;
      cvt8(hhA, &ahiA, &aloA);
      cvt8(hhB, &ahiB, &aloB);
#pragma unroll
      for (int nt = 0; nt < 2; ++nt) {
        int ntb = w * 2 + nt;
        size_t off = ((size_t)(ntb * 4 + ks) * 64 + l) * 8;
        bf16x8 bhi = *(const bf16x8*)(Whi + off);
        bf16x8 blo = *(const bf16x8*)(Wlo + off);
        acc2A[nt] = __builtin_amdgcn_mfma_f32_16x16x32_bf16(ahiA, bhi, acc2A[nt], 0, 0, 0);
        acc2A[nt] = __builtin_amdgcn_mfma_f32_16x16x32_bf16(ahiA, blo, acc2A[nt], 0, 0, 0);
        acc2A[nt] = __builtin_amdgcn_mfma_f32_16x16x32_bf16(aloA, bhi, acc2A[nt], 0, 0, 0);
        acc2B[nt] = __builtin_amdgcn_mfma_f32_16x16x32_bf16(ahiB, bhi, acc2B[nt], 0, 0, 0);
        acc2B[nt] = __builtin_amdgcn_mfma_f32_16x16x32_bf16(ahiB, blo, acc2B[nt], 0, 0, 0);
        acc2B[nt] = __builtin_amdgcn_mfma_f32_16x16x32_bf16(aloB, bhi, acc2B[nt], 0, 0, 0);
      }
    }
#pragma unroll
    for (int nt = 0; nt < 2; ++nt) {
      int ntb = w * 2 + nt;
      int col = ntb * 16 + c;
      float bv = b2[col];
#pragma unroll
      for (int r = 0; r < 4; ++r) {
        int row = grp * 4 + r;
        if (vA) {
          int onode = perm[mtA * 16 + row] & 0xFFFF;
          size_t idx = (size_t)onode * DD + col;
          unsigned short rb = rtile[0][row * 136 + col];
          float v = acc2A[nt][r] + bv + (float)(*(_Float16*)&rb);
          if (OUT_F32) Xf_out[idx] = v; else Xh_out[idx] = (_Float16)v;
        }
        if (vB) {
          int onode = perm[mtB * 16 + row] & 0xFFFF;
          size_t idx = (size_t)onode * DD + col;
          unsigned short rb = rtile[1][row * 136 + col];
          float v = acc2B[nt][r] + bv + (float)(*(_Float16*)&rb);
          if (OUT_F32) Xf_out[idx] = v; else Xh_out[idx] = (_Float16)v;
        }
      }
    }
  }
}

extern "C" void kernel_launch(void* const* d_in, const int* in_sizes, int n_in,
                              void* d_out, int out_size, void* d_ws, size_t ws_size,
                              hipStream_t stream) {
  const float* X   = (const float*)d_in[0];
  const int*   ei  = (const int*)d_in[1];
  const float* eps = (const float*)d_in[2];
  const float* W1  = (const float*)d_in[3];
  const float* b1  = (const float*)d_in[4];
  const float* W2  = (const float*)d_in[5];
  const float* b2  = (const float*)d_in[6];
  float* Xout = (float*)d_out;

  char* ws = (char*)d_ws;
  size_t off = 0;
  int* cnt  = (int*)(ws + off); off += 256 * (((size_t)NN * 4 + 255) / 256);
  int* perm = (int*)(ws + off); off += 256 * (((size_t)(MT_PER_XCD * 8 * 16) * 4 + 255) / 256);
  unsigned short* ell = (unsigned short*)(ws + off); off += (size_t)NN * ELLW * 2;
  unsigned short* Wp  = (unsigned short*)(ws + off); off += (size_t)6 * 2 * DD * DD * 2;
  off = 256 * ((off + 255) / 256);
  _Float16* Xh0 = (_Float16*)(ws + off); off += (size_t)NN * DD * 2;
  _Float16* Xh1 = (_Float16*)(ws + off); off += (size_t)NN * DD * 2;

  hipMemsetAsync(cnt, 0, (size_t)NN * 4, stream);
  prologue_k<<<SCAT_BLKS + PACK_BLKS + INIT_BLKS, 256, 0, stream>>>(
      ei, cnt, ell, W1, W2, Wp, X, Xh0);
  sort_k<<<8, 256, 0, stream>>>(cnt, perm);

  const int fgrid = NPAIR * 8;  // 1568 blocks, 2 tiles each
  fused_layer_k<0><<<fgrid, 256, 0, stream>>>(Xh0, perm, ell, eps, 0,
      Wp + (size_t)0 * 2 * DD * DD, b1 + 0 * DD,
      Wp + (size_t)3 * 2 * DD * DD, b2 + 0 * DD, nullptr, Xh1);
  fused_layer_k<0><<<fgrid, 256, 0, stream>>>(Xh1, perm, ell, eps, 1,
      Wp + (size_t)1 * 2 * DD * DD, b1 + 1 * DD,
      Wp + (size_t)4 * 2 * DD * DD, b2 + 1 * DD, nullptr, Xh0);
  fused_layer_k<1><<<fgrid, 256, 0, stream>>>(Xh0, perm, ell, eps, 2,
      Wp + (size_t)2 * 2 * DD * DD, b1 + 2 * DD,
      Wp + (size_t)5 * 2 * DD * DD, b2 + 2 * DD, Xout, nullptr);
}

// Round 20
// 186.653 us; speedup vs baseline: 1.2000x; 1.2000x over previous
//
#include <hip/hip_runtime.h>

#define NN 50000
#define NE 800000
#define DD 128
#define NL 3
#define ELLW 64
#define MT_TOTAL (NN / 16)                      // 3125 tiles of 16 rows
#define MT_PER_XCD 391                          // ceil(3128/8); grid pad to 3128
#define NODES_PER_XCD (MT_PER_XCD * 16)         // 6256
#define SCAT_BLKS (MT_PER_XCD * 8)              // 3128 (residue g scans all edges)
#define SCAT_CHUNK 2048
#define PACK_BLKS ((6 * 2048 + 255) / 256)      // 48 (multiple of 8)
#define INIT_BLKS 3128                          // swizzled fp16-mirror init

typedef short bf16x8 __attribute__((ext_vector_type(8)));
typedef float f32x4 __attribute__((ext_vector_type(4)));
typedef _Float16 half8 __attribute__((ext_vector_type(8)));
typedef unsigned short u16x8 __attribute__((ext_vector_type(8)));

__device__ __forceinline__ unsigned short f2bf(float x) {
  unsigned u = __float_as_uint(x);
  u += 0x7FFFu + ((u >> 16) & 1u);          // RTN-even
  return (unsigned short)(u >> 16);
}
__device__ __forceinline__ float bf2f(unsigned short h) {
  return __uint_as_float(((unsigned)h) << 16);
}
__device__ __forceinline__ void cvt8(const float* zz, bf16x8* hi, bf16x8* lo) {
#pragma unroll
  for (int i = 0; i < 8; ++i) {
    unsigned short h = f2bf(zz[i]);
    (*hi)[i] = (short)h;
    (*lo)[i] = (short)f2bf(zz[i] - bf2f(h));
  }
}

// ---------------- fused prologue: XCD-filtered ELL build + W pack + fp16 mirror ----
__global__ __launch_bounds__(256) void prologue_k(
    const int* __restrict__ ei, int* __restrict__ cnt, unsigned short* __restrict__ ell,
    const float* __restrict__ W1, const float* __restrict__ W2,
    unsigned short* __restrict__ Wp,
    const float* __restrict__ X, _Float16* __restrict__ Xh)
{
  int b = blockIdx.x;
  if (b < SCAT_BLKS) {
    int g = b & 7, chunk = b >> 3;
    int lo = g * NODES_PER_XCD, hi = lo + NODES_PER_XCD;
    int base = chunk * SCAT_CHUNK + threadIdx.x * 8;
    if (base + 7 < NE) {
      int4 d0 = *(const int4*)(ei + NE + base);
      int4 d1 = *(const int4*)(ei + NE + base + 4);
      int4 s0 = *(const int4*)(ei + base);
      int4 s1 = *(const int4*)(ei + base + 4);
      int dd[8] = {d0.x, d0.y, d0.z, d0.w, d1.x, d1.y, d1.z, d1.w};
      int ss[8] = {s0.x, s0.y, s0.z, s0.w, s1.x, s1.y, s1.z, s1.w};
#pragma unroll
      for (int i = 0; i < 8; ++i) {
        int d = dd[i];
        if (d >= lo && d < hi) {
          int pos = atomicAdd(&cnt[d], 1);
          if (pos < ELLW) ell[(size_t)d * ELLW + pos] = (unsigned short)ss[i];
        }
      }
    } else {
      for (int e = base; e < NE; ++e) {
        int d = ei[NE + e];
        if (d >= lo && d < hi) {
          int pos = atomicAdd(&cnt[d], 1);
          if (pos < ELLW) ell[(size_t)d * ELLW + pos] = (unsigned short)ei[e];
        }
      }
    }
  } else if (b < SCAT_BLKS + PACK_BLKS) {
    int t = (b - SCAT_BLKS) * 256 + threadIdx.x;
    if (t < 6 * 2048) {
      int m = t >> 11;
      int rem = t & 2047;              // (nt*4+ks)*64 + lane
      int l = rem & 63;
      int ntks = rem >> 6;
      int ks = ntks & 3, nt = ntks >> 2;
      const float* W = (m < 3) ? (W1 + (size_t)m * DD * DD) : (W2 + (size_t)(m - 3) * DD * DD);
      int col = nt * 16 + (l & 15);
      int k0 = ks * 32 + (l >> 4) * 8;
      unsigned short* hi = Wp + (size_t)m * 2 * DD * DD + (size_t)rem * 8;
      unsigned short* lo = hi + DD * DD;
#pragma unroll
      for (int i = 0; i < 8; ++i) {
        float w = W[(size_t)(k0 + i) * DD + col];
        unsigned short h = f2bf(w);
        hi[i] = h;
        lo[i] = f2bf(w - bf2f(h));
      }
    }
  } else {
    int bb = b - SCAT_BLKS - PACK_BLKS;
    int g = bb & 7, ii = bb >> 3;
    int mt = g * MT_PER_XCD + ii;
    if (mt < MT_TOTAL) {
      size_t base = (size_t)mt * 16 * DD + threadIdx.x * 8;
      const float4* p = (const float4*)(X + base);
      float4 a = p[0], bb2 = p[1];
      half8 h;
      h[0] = (_Float16)a.x;   h[1] = (_Float16)a.y;   h[2] = (_Float16)a.z;   h[3] = (_Float16)a.w;
      h[4] = (_Float16)bb2.x; h[5] = (_Float16)bb2.y; h[6] = (_Float16)bb2.z; h[7] = (_Float16)bb2.w;
      *(half8*)(Xh + base) = h;
    }
  }
}

// ---------------- single-kernel per-partition counting sort -> perm ----------------
__global__ __launch_bounds__(256) void sort_k(const int* __restrict__ cnt,
                                              int* __restrict__ perm) {
  __shared__ int lh[ELLW + 1];
  __shared__ int cur[ELLW + 1];
  int g = blockIdx.x;
  int base = g * NODES_PER_XCD;
  int nend = base + NODES_PER_XCD; if (nend > NN) nend = NN;
  for (int i = threadIdx.x; i <= ELLW; i += 256) lh[i] = 0;
  __syncthreads();
  for (int n = base + threadIdx.x; n < nend; n += 256) {
    int deg = cnt[n]; deg = deg > ELLW ? ELLW : deg;
    atomicAdd(&lh[deg], 1);
  }
  __syncthreads();
  if (threadIdx.x == 0) {
    int run = base;
    for (int b = 0; b <= ELLW; ++b) { cur[b] = run; run += lh[b]; }
  }
  __syncthreads();
  for (int n = base + threadIdx.x; n < nend; n += 256) {
    int deg = cnt[n]; deg = deg > ELLW ? ELLW : deg;
    int rank = atomicAdd(&cur[deg], 1);
    perm[rank] = n | (deg << 16);
  }
}

// ---------------- fused layer: aggregate -> GEMM1+ReLU -> GEMM2+resid ----------------
// Deg-homogeneous tiles; block->tile remapped with stride 7 (coprime to 391) so
// co-resident blocks carry DIFFERENT degrees -> desynchronized phases overlap.
template<int OUT_F32>
__global__ __launch_bounds__(256) void fused_layer_k(
    const _Float16* __restrict__ Xh_in,
    const int* __restrict__ perm, const unsigned short* __restrict__ ell,
    const float* __restrict__ eps, int layer,
    const unsigned short* __restrict__ Wp1, const float* __restrict__ b1,
    const unsigned short* __restrict__ Wp2, const float* __restrict__ b2,
    float* __restrict__ Xf_out, _Float16* __restrict__ Xh_out)
{
  __shared__ float ztile[16 * 132];          // Z then H; pitch 132
  __shared__ unsigned short rtile[16 * 136]; // fp16 residual stash
  const int part = blockIdx.x & 7;
  const int ii = blockIdx.x >> 3;
  const int iis = (ii * 7) % MT_PER_XCD;     // gcd(7,391)=1: bijective shuffle
  const int mt = part * MT_PER_XCD + iis;
  if (mt >= MT_TOTAL) return;
  const int w = threadIdx.x >> 6, l = threadIdx.x & 63;
  const int c = l & 15, grp = l >> 4;

  // ---- phase A: aggregation (4 nodes per wave, 16 lanes each, fp16 packed) ----
  {
    const float e1 = 1.0f + eps[layer];
    const int nl = w * 4 + grp;
    const int pe = perm[mt * 16 + nl];
    const int node = pe & 0xFFFF;
    const int deg = pe >> 16;
    const unsigned short* el = ell + (size_t)node * ELLW;
    const u16x8* el8 = (const u16x8*)el;
    half8 sv = *(const half8*)(Xh_in + (size_t)node * DD + c * 8);
    *(u16x8*)(rtile + nl * 136 + c * 8) = *(const u16x8*)&sv;
    half8 acch = (half8)(_Float16)0.0f;
    int nf8 = deg >> 3;
    u16x8 nxt;
    if (nf8) nxt = el8[0];
    for (int t = 0; t < nf8; ++t) {
      u16x8 cur = nxt;
      if (t + 1 < nf8) nxt = el8[t + 1];
      half8 v0 = *(const half8*)(Xh_in + (size_t)cur[0] * DD + c * 8);
      half8 v1 = *(const half8*)(Xh_in + (size_t)cur[1] * DD + c * 8);
      half8 v2 = *(const half8*)(Xh_in + (size_t)cur[2] * DD + c * 8);
      half8 v3 = *(const half8*)(Xh_in + (size_t)cur[3] * DD + c * 8);
      half8 v4 = *(const half8*)(Xh_in + (size_t)cur[4] * DD + c * 8);
      half8 v5 = *(const half8*)(Xh_in + (size_t)cur[5] * DD + c * 8);
      half8 v6 = *(const half8*)(Xh_in + (size_t)cur[6] * DD + c * 8);
      half8 v7 = *(const half8*)(Xh_in + (size_t)cur[7] * DD + c * 8);
      half8 s = ((v0 + v1) + (v2 + v3)) + ((v4 + v5) + (v6 + v7));
      acch += s;
    }
    for (int j = nf8 * 8; j < deg; ++j) {
      half8 v = *(const half8*)(Xh_in + (size_t)el[j] * DD + c * 8);
      acch += v;
    }
    float acc[8];
#pragma unroll
    for (int i = 0; i < 8; ++i) acc[i] = fmaf(e1, (float)sv[i], (float)acch[i]);
    float* dst = ztile + nl * 132 + c * 8;
    *(float4*)dst = make_float4(acc[0], acc[1], acc[2], acc[3]);
    *(float4*)(dst + 4) = make_float4(acc[4], acc[5], acc[6], acc[7]);
  }
  __syncthreads();

  // ---- phase B: GEMM1 (Z @ W1) on 2 column-tiles, ReLU, H -> LDS ----
  f32x4 acc1[2];
#pragma unroll
  for (int nt = 0; nt < 2; ++nt) acc1[nt] = (f32x4){0.f, 0.f, 0.f, 0.f};
  {
    const float* arow = ztile + (l & 15) * 132;
    const unsigned short* Whi = Wp1;
    const unsigned short* Wlo = Wp1 + DD * DD;
#pragma unroll
    for (int ks = 0; ks < 4; ++ks) {
      const float* zp = arow + ks * 32 + grp * 8;
      float zz[8] = {zp[0], zp[1], zp[2], zp[3], zp[4], zp[5], zp[6], zp[7]};
      bf16x8 ahi, alo; cvt8(zz, &ahi, &alo);
#pragma unroll
      for (int nt = 0; nt < 2; ++nt) {
        int ntb = w * 2 + nt;
        size_t off = ((size_t)(ntb * 4 + ks) * 64 + l) * 8;
        bf16x8 bhi = *(const bf16x8*)(Whi + off);
        bf16x8 blo = *(const bf16x8*)(Wlo + off);
        acc1[nt] = __builtin_amdgcn_mfma_f32_16x16x32_bf16(ahi, bhi, acc1[nt], 0, 0, 0);
        acc1[nt] = __builtin_amdgcn_mfma_f32_16x16x32_bf16(ahi, blo, acc1[nt], 0, 0, 0);
        acc1[nt] = __builtin_amdgcn_mfma_f32_16x16x32_bf16(alo, bhi, acc1[nt], 0, 0, 0);
      }
    }
  }
  __syncthreads();   // all Z reads complete before H overwrites the tile

  {
#pragma unroll
    for (int nt = 0; nt < 2; ++nt) {
      int ntb = w * 2 + nt;
      float bv = b1[ntb * 16 + c];
#pragma unroll
      for (int r = 0; r < 4; ++r)
        ztile[(grp * 4 + r) * 132 + ntb * 16 + c] = fmaxf(acc1[nt][r] + bv, 0.f);
    }
  }
  __syncthreads();

  // ---- phase C: GEMM2 (H @ W2) + bias + residual(LDS fp16), write state/output ----
  f32x4 acc2[2];
#pragma unroll
  for (int nt = 0; nt < 2; ++nt) acc2[nt] = (f32x4){0.f, 0.f, 0.f, 0.f};
  {
    const float* arow = ztile + (l & 15) * 132;
    const unsigned short* Whi = Wp2;
    const unsigned short* Wlo = Wp2 + DD * DD;
#pragma unroll
    for (int ks = 0; ks < 4; ++ks) {
      const float* hp = arow + ks * 32 + grp * 8;
      float hh[8] = {hp[0], hp[1], hp[2], hp[3], hp[4], hp[5], hp[6], hp[7]};
      bf16x8 ahi, alo; cvt8(hh, &ahi, &alo);
#pragma unroll
      for (int nt = 0; nt < 2; ++nt) {
        int ntb = w * 2 + nt;
        size_t off = ((size_t)(ntb * 4 + ks) * 64 + l) * 8;
        bf16x8 bhi = *(const bf16x8*)(Whi + off);
        bf16x8 blo = *(const bf16x8*)(Wlo + off);
        acc2[nt] = __builtin_amdgcn_mfma_f32_16x16x32_bf16(ahi, bhi, acc2[nt], 0, 0, 0);
        acc2[nt] = __builtin_amdgcn_mfma_f32_16x16x32_bf16(ahi, blo, acc2[nt], 0, 0, 0);
        acc2[nt] = __builtin_amdgcn_mfma_f32_16x16x32_bf16(alo, bhi, acc2[nt], 0, 0, 0);
      }
    }
#pragma unroll
    for (int nt = 0; nt < 2; ++nt) {
      int ntb = w * 2 + nt;
      int col = ntb * 16 + c;
      float bv = b2[col];
#pragma unroll
      for (int r = 0; r < 4; ++r) {
        int row = grp * 4 + r;
        int onode = perm[mt * 16 + row] & 0xFFFF;
        size_t idx = (size_t)onode * DD + col;
        unsigned short rb = rtile[row * 136 + col];
        float rv = (float)(*(_Float16*)&rb);
        float v = acc2[nt][r] + bv + rv;
        if (OUT_F32) Xf_out[idx] = v;
        else         Xh_out[idx] = (_Float16)v;
      }
    }
  }
}

extern "C" void kernel_launch(void* const* d_in, const int* in_sizes, int n_in,
                              void* d_out, int out_size, void* d_ws, size_t ws_size,
                              hipStream_t stream) {
  const float* X   = (const float*)d_in[0];
  const int*   ei  = (const int*)d_in[1];
  const float* eps = (const float*)d_in[2];
  const float* W1  = (const float*)d_in[3];
  const float* b1  = (const float*)d_in[4];
  const float* W2  = (const float*)d_in[5];
  const float* b2  = (const float*)d_in[6];
  float* Xout = (float*)d_out;

  char* ws = (char*)d_ws;
  size_t off = 0;
  int* cnt  = (int*)(ws + off); off += 256 * (((size_t)NN * 4 + 255) / 256);
  int* perm = (int*)(ws + off); off += 256 * (((size_t)(MT_PER_XCD * 8 * 16) * 4 + 255) / 256);
  unsigned short* ell = (unsigned short*)(ws + off); off += (size_t)NN * ELLW * 2;
  unsigned short* Wp  = (unsigned short*)(ws + off); off += (size_t)6 * 2 * DD * DD * 2;
  off = 256 * ((off + 255) / 256);
  _Float16* Xh0 = (_Float16*)(ws + off); off += (size_t)NN * DD * 2;
  _Float16* Xh1 = (_Float16*)(ws + off); off += (size_t)NN * DD * 2;

  hipMemsetAsync(cnt, 0, (size_t)NN * 4, stream);
  prologue_k<<<SCAT_BLKS + PACK_BLKS + INIT_BLKS, 256, 0, stream>>>(
      ei, cnt, ell, W1, W2, Wp, X, Xh0);
  sort_k<<<8, 256, 0, stream>>>(cnt, perm);

  const int fgrid = MT_PER_XCD * 8;  // 3128 blocks (3 all-pad, dropped by guard)
  fused_layer_k<0><<<fgrid, 256, 0, stream>>>(Xh0, perm, ell, eps, 0,
      Wp + (size_t)0 * 2 * DD * DD, b1 + 0 * DD,
      Wp + (size_t)3 * 2 * DD * DD, b2 + 0 * DD, nullptr, Xh1);
  fused_layer_k<0><<<fgrid, 256, 0, stream>>>(Xh1, perm, ell, eps, 1,
      Wp + (size_t)1 * 2 * DD * DD, b1 + 1 * DD,
      Wp + (size_t)4 * 2 * DD * DD, b2 + 1 * DD, nullptr, Xh0);
  fused_layer_k<1><<<fgrid, 256, 0, stream>>>(Xh0, perm, ell, eps, 2,
      Wp + (size_t)2 * 2 * DD * DD, b1 + 2 * DD,
      Wp + (size_t)5 * 2 * DD * DD, b2 + 2 * DD, Xout, nullptr);
}